// Round 10
// baseline (381.117 us; speedup 1.0000x reference)
//
#include <hip/hip_runtime.h>

#define BB 16
#define NN 4096
#define CC 128
#define PP 1024
#define SS 32
#define MM (BB*PP*SS)       // 524288
#define NBLK 8192           // stat-partial stride
#define OFF_NF 49152        // 16*1024*3
#define OFF_SI 4243456      // 49152 + 16*256*1024

typedef unsigned short u16;
typedef unsigned int u32;
typedef __attribute__((ext_vector_type(8))) short short8v;
typedef __attribute__((ext_vector_type(4))) float f32x4;

__device__ __forceinline__ float b2f(u16 u) {
    union { float f; unsigned i; } x; x.i = ((unsigned)u) << 16; return x.f;
}
__device__ __forceinline__ u16 f2b(float f) {   // RTNE bf16
    union { float f; unsigned i; } x; x.f = f;
    unsigned r = x.i + 0x7fffu + ((x.i >> 16) & 1u);
    return (u16)(r >> 16);
}
__device__ __forceinline__ float2 act2(u32 u, float2 s0, float2 s1) {
    union { float f; unsigned i; } a, b;
    a.i = u << 16; b.i = u & 0xffff0000u;
    return make_float2(fmaxf(fmaf(s0.x, a.f, s0.y), 0.f),
                       fmaxf(fmaf(s1.x, b.f, s1.y), 0.f));
}
// unpack 2 bf16 (lo, hi) from one u32
__device__ __forceinline__ float2 unpk2(u32 u) {
    union { float f; unsigned i; } a, b;
    a.i = u << 16; b.i = u & 0xffff0000u;
    return make_float2(a.f, b.f);
}
__device__ __forceinline__ u32 packbf(float flo, float fhi) {
    union { float f; unsigned i; } x0, x1; x0.f = flo; x1.f = fhi;
    return __builtin_amdgcn_perm(x1.i, x0.i, 0x07060302u);
}
__device__ __forceinline__ u32 packbf_rtne(float flo, float fhi) {
    union { float f; unsigned i; } x0, x1; x0.f = flo; x1.f = fhi;
    u32 r0 = x0.i + 0x7fffu + ((x0.i >> 16) & 1u);
    u32 r1 = x1.i + 0x7fffu + ((x1.i >> 16) & 1u);
    return __builtin_amdgcn_perm(r1, r0, 0x07060302u);
}
__device__ __forceinline__ u32 act_pack(u32 u, float2 s0, float2 s1) {
    float2 f = act2(u, s0, s1);
    return packbf(f.x, f.y);
}
__device__ __forceinline__ short8v as_s8(uint4 v) {
    union { uint4 u; short8v s; } x; x.u = v; return x.s;
}

#define MFMA16(a,b,c) __builtin_amdgcn_mfma_f32_16x16x32_bf16(a,b,c,0,0,0)

// ---------------------------------------------------------------------------
// k_init: new_xyz + sample_idxs + w0t (xyz rows, fp32) + w0b/w1b/w2b (bf16)
// ---------------------------------------------------------------------------
__global__ void k_init(const float* __restrict__ xyz, const float* __restrict__ w0,
                       const float* __restrict__ w1, const float* __restrict__ w2,
                       float* __restrict__ out, float* __restrict__ w0t,
                       u16* __restrict__ w0b, u16* __restrict__ w1b,
                       u16* __restrict__ w2b) {
    int i = blockIdx.x * 256 + threadIdx.x;
    if (i < 49152) {
        int b = i / 3072, r = i % 3072;
        out[i] = xyz[b * 12288 + r];
        return;
    }
    int j = i - 49152;
    if (j < 16384) { out[OFF_SI + j] = (float)(j & 1023); return; }
    int e = j - 16384;
    if (e < 384) { w0t[e] = w0[(e & 127) * 131 + (e >> 7)]; return; }
    int f = e - 384;
    if (f < 16384) { w0b[f] = f2b(w0[(f >> 7) * 131 + 3 + (f & 127)]); return; }
    int h = f - 16384;
    if (h < 16384) { w1b[h] = f2b(w1[h]); return; }
    int k2 = h - 16384;
    if (k2 < 32768) { w2b[k2] = f2b(w2[k2]); }
}

// ---------------------------------------------------------------------------
// k_bqf1: FUSED ballquery + f1. 16 centers per bq block (wave scans 4 from
// one staged 48KB xyz tile). Grid 2048: even = f1 tile, odd = bq block.
// LDS = 48KB union (bq sx/sy/sz >= f1 abuf 17408 B).
// ---------------------------------------------------------------------------
__global__ __launch_bounds__(256) void k_bqf1(const float* __restrict__ xyz,
                                              const float* __restrict__ feat,
                                              const u16* __restrict__ w0b,
                                              float4* __restrict__ rel4,
                                              u16* __restrict__ F1) {
    __shared__ __align__(16) float smem[12288];   // 48 KB union
    int bid = blockIdx.x;
    int q2 = bid >> 1;
    int t = threadIdx.x;
    if (!(bid & 1)) {
        // ---------------- f1 tile q2: F1[n][co] = feat . w0b -------------
        uint4* abuf = (uint4*)smem;               // 64*17 uint4 = 17408 B
        int fb = q2;
        int w = t >> 6, lane = t & 63, q = lane >> 4, l16 = lane & 15;
        int cb = (w & 1) * 64, wm0 = (w >> 1) * 32;
        short8v bf[4][4];
#pragma unroll
        for (int ct = 0; ct < 4; ++ct)
#pragma unroll
            for (int k0 = 0; k0 < 4; ++k0)
                bf[ct][k0] = *(const short8v*)(w0b + (cb + ct * 16 + l16) * 128 + k0 * 32 + q * 8);
        int nl = t & 63, cg = t >> 6;
        const float* fcol = feat + (long)(fb >> 6) * (128 * 4096)
                                 + (long)(fb & 63) * 64 + nl;
#pragma unroll
        for (int pp = 0; pp < 4; ++pp) {
            int oct = cg + 4 * pp;
            float v[8];
#pragma unroll
            for (int r = 0; r < 8; ++r) v[r] = fcol[(long)(oct * 8 + r) * 4096];
            uint4 ov;
            ov.x = packbf_rtne(v[0], v[1]); ov.y = packbf_rtne(v[2], v[3]);
            ov.z = packbf_rtne(v[4], v[5]); ov.w = packbf_rtne(v[6], v[7]);
            abuf[nl * 17 + ((oct + nl) & 15)] = ov;
        }
        __syncthreads();
        f32x4 acc[2][4];
#pragma unroll
        for (int mt = 0; mt < 2; ++mt)
#pragma unroll
            for (int ct = 0; ct < 4; ++ct) acc[mt][ct] = (f32x4){0.f, 0.f, 0.f, 0.f};
#pragma unroll
        for (int mt = 0; mt < 2; ++mt) {
            int row = wm0 + mt * 16 + l16;
#pragma unroll
            for (int k0 = 0; k0 < 4; ++k0) {
                uint4 vv = abuf[row * 17 + ((k0 * 4 + q + row) & 15)];
                short8v af = as_s8(vv);
#pragma unroll
                for (int ct = 0; ct < 4; ++ct)
                    acc[mt][ct] = MFMA16(af, bf[ct][k0], acc[mt][ct]);
            }
        }
        long nbase = (long)fb * 64;
#pragma unroll
        for (int mt = 0; mt < 2; ++mt)
#pragma unroll
            for (int ct = 0; ct < 4; ++ct)
#pragma unroll
                for (int r = 0; r < 4; ++r)
                    F1[(nbase + wm0 + mt * 16 + q * 4 + r) * 128 + cb + ct * 16 + l16]
                        = f2b(acc[mt][ct][r]);
    } else {
        // -------- ballquery block q2: 16 centers, wave w scans 4 --------
        float* sx = smem;
        float* sy = smem + 4096;
        float* sz = smem + 8192;
        int w = t >> 6, lane = t & 63;
        int b = q2 >> 6;                   // 64 bq blocks per batch
        int pbase = (q2 & 63) * 16;
        const float* xb = xyz + (long)b * NN * 3;
        for (int i = t; i < NN; i += 256) {
            sx[i] = xb[3 * i]; sy[i] = xb[3 * i + 1]; sz[i] = xb[3 * i + 2];
        }
        __syncthreads();
        const float R2 = (float)(0.4 * 0.4);
#pragma unroll 1
        for (int k = 0; k < 4; ++k) {
            int p = pbase + 4 * w + k;
            float cx = sx[p], cy = sy[p], cz = sz[p];
            int o = (b * PP + p) * SS;
            int cnt = 0, firstn = 0;
            float fdx = 0.f, fdy = 0.f, fdz = 0.f;
            for (int c = 0; c < 64 && cnt < 32; ++c) {
                int n = c * 64 + lane;
                float dx = __fsub_rn(sx[n], cx);
                float dy = __fsub_rn(sy[n], cy);
                float dz = __fsub_rn(sz[n], cz);
                float d2 = __fadd_rn(__fadd_rn(__fmul_rn(dx, dx), __fmul_rn(dy, dy)),
                                     __fmul_rn(dz, dz));
                bool hit = d2 < R2;
                unsigned long long mask = __ballot(hit);
                if (mask) {
                    if (cnt == 0) {
                        int fl = __ffsll(mask) - 1;
                        firstn = c * 64 + fl;
                        fdx = __shfl(dx, fl); fdy = __shfl(dy, fl); fdz = __shfl(dz, fl);
                    }
                    int pos = cnt + __popcll(mask & ((1ull << lane) - 1ull));
                    if (hit && pos < 32) {
                        rel4[o + pos] = make_float4(dx, dy, dz, __int_as_float(n));
                    }
                    cnt += __popcll(mask);
                }
            }
            if (lane < 32 && lane >= cnt) {
                rel4[o + lane] = make_float4(fdx, fdy, fdz, __int_as_float(firstn));
            }
        }
    }
}

// ---------------------------------------------------------------------------
// k_y0stats: BN0 partials without materializing y0. rel4 staged to LDS;
// F1 (bf16) gathers batched 16-deep with one-group-ahead prefetch.
// ---------------------------------------------------------------------------
__global__ __launch_bounds__(256) void k_y0stats(const float4* __restrict__ rel4,
                                                 const float* __restrict__ w0t,
                                                 const u16* __restrict__ F1,
                                                 float* __restrict__ part,
                                                 float* __restrict__ partq) {
    __shared__ float4 srel[256];
    int t = threadIdx.x, w = t >> 6, lane = t & 63;
    int c0 = 2 * lane;
    float wx0 = w0t[c0],       wx1 = w0t[c0 + 1];
    float wy0 = w0t[128 + c0], wy1 = w0t[128 + c0 + 1];
    float wz0 = w0t[256 + c0], wz1 = w0t[256 + c0 + 1];
    int m0 = blockIdx.x * 256;
    srel[t] = rel4[m0 + t];
    __syncthreads();
    // whole block shares one batch b (256 | 32768)
    const u16* F1b = F1 + (((long)(blockIdx.x >> 7) * NN) << 7) + c0;
    float s1a = 0.f, s1b = 0.f, s2a = 0.f, s2b = 0.f;
    u32 f[16];
#pragma unroll
    for (int j = 0; j < 16; ++j) {
        int id = __float_as_int(srel[w + 4 * j].w);
        f[j] = *(const u32*)(F1b + ((long)id << 7));
    }
#pragma unroll
    for (int g = 0; g < 4; ++g) {
        u32 fn[16];
        if (g < 3) {
#pragma unroll
            for (int j = 0; j < 16; ++j) {
                int id = __float_as_int(srel[w + 4 * (16 * (g + 1) + j)].w);
                fn[j] = *(const u32*)(F1b + ((long)id << 7));
            }
        }
#pragma unroll
        for (int j = 0; j < 16; ++j) {
            float4 qv = srel[w + 4 * (16 * g + j)];
            float2 ff = unpk2(f[j]);
            float v0 = fmaf(wx0, qv.x, fmaf(wy0, qv.y, fmaf(wz0, qv.z, ff.x)));
            float v1 = fmaf(wx1, qv.x, fmaf(wy1, qv.y, fmaf(wz1, qv.z, ff.y)));
            s1a += v0; s2a = fmaf(v0, v0, s2a);
            s1b += v1; s2b = fmaf(v1, v1, s2b);
        }
#pragma unroll
        for (int j = 0; j < 16; ++j) f[j] = fn[j];
    }
    __shared__ float r1[128][4], r2[128][4];
    r1[c0][w] = s1a; r1[c0 + 1][w] = s1b;
    r2[c0][w] = s2a; r2[c0 + 1][w] = s2b;
    __syncthreads();
    if (t < 128) {
        float a1 = r1[t][0] + r1[t][1] + r1[t][2] + r1[t][3];
        float a2 = r2[t][0] + r2[t][1] + r2[t][2] + r2[t][3];
        part [(long)t * NBLK + blockIdx.x] = a1;
        partq[(long)t * NBLK + blockIdx.x] = a2;
    }
}

// ---------------------------------------------------------------------------
// k_bnfin: reduce per-channel partials -> (scale, shift). grid = #channels.
// ---------------------------------------------------------------------------
__global__ void k_bnfin(const float* __restrict__ part, const float* __restrict__ partq,
                        const float* __restrict__ g, const float* __restrict__ beta,
                        float* __restrict__ st, int nblk) {
    int co = blockIdx.x, t = threadIdx.x;
    const float* p1 = part + (long)co * NBLK;
    const float* p2 = partq + (long)co * NBLK;
    float s1 = 0.f, s2 = 0.f;
    for (int j = t; j < nblk; j += 256) { s1 += p1[j]; s2 += p2[j]; }
    __shared__ float r1[256], r2[256];
    r1[t] = s1; r2[t] = s2; __syncthreads();
    for (int off = 128; off > 0; off >>= 1) {
        if (t < off) { r1[t] += r1[t + off]; r2[t] += r2[t + off]; }
        __syncthreads();
    }
    if (t == 0) {
        const float inv = 1.f / (float)MM;
        float mean = r1[0] * inv;
        float var = r2[0] * inv - mean * mean;
        float sc = g[co] * rsqrtf(var + 1e-5f);
        st[2 * co] = sc;
        st[2 * co + 1] = fmaf(-mean, sc, beta[co]);
    }
}

// ---------------------------------------------------------------------------
// k_conv1: y1 = W1 . act0(y0), act0(y0) reconstructed in staging from
// srel (LDS copy of rel4) + F1 (bf16) gather + st0. THIS ROUND: abuf
// single-buffered (17408 B) -> LDS 27648 B -> 5 blocks/CU (was 3 at
// 45056 B), launch_bounds(256,5) (VGPR cap 102 >= current 84, no spill
// -- unlike r6's (256,4) which demanded <=64 and spilled). Grid 1024 <
// 1280 capacity -> zero residency tail. Cost: 2nd syncthreads per chunk
// (stage -> sync -> MFMA+epi -> sync). Stride-17 rotation swizzle kept
// (r6: stride-16 -> 1M bank conflicts. Do not repeat).
// ---------------------------------------------------------------------------
__global__ __launch_bounds__(256, 5) void k_conv1(const float4* __restrict__ rel4,
                                                  const u16* __restrict__ F1,
                                                  const u16* __restrict__ w1b,
                                                  const float* __restrict__ w0t,
                                                  const float* __restrict__ st0,
                                                  u16* __restrict__ y,
                                                  float* __restrict__ part,
                                                  float* __restrict__ partq) {
    __shared__ u32 abuf[64 * 17 * 4];      // 17408 B, single buffer
    __shared__ float4 srel[512];           // 8192 B
    __shared__ float sredA[4][64], sredB[4][64];  // 2048 B
    int t = threadIdx.x;
    int w = t >> 6, lane = t & 63, q = lane >> 4, l16 = lane & 15;
    int wm0 = (w >> 1) * 32, cb = (w & 1) * 64;
    short8v bf[4][4];
#pragma unroll
    for (int ct = 0; ct < 4; ++ct)
#pragma unroll
        for (int k0 = 0; k0 < 4; ++k0)
            bf[ct][k0] = *(const short8v*)(w1b + (cb + ct * 16 + l16) * 128 + k0 * 32 + q * 8);
    // staging constants for cols (2*lane, 2*lane+1)
    int c0 = 2 * lane;
    float wx0 = w0t[c0],       wx1 = w0t[c0 + 1];
    float wy0 = w0t[128 + c0], wy1 = w0t[128 + c0 + 1];
    float wz0 = w0t[256 + c0], wz1 = w0t[256 + c0 + 1];
    float4 s4 = *(const float4*)(st0 + 2 * c0);   // sc0, sh0, sc1, sh1
    int m0b = blockIdx.x * 512;
    // stage rel4 for the whole block into LDS (coalesced, once)
    srel[t] = rel4[m0b + t];
    srel[t + 256] = rel4[m0b + t + 256];
    __syncthreads();
    // whole block shares one batch b (512 | 32768)
    const u16* F1b = F1 + (((long)(blockIdx.x >> 6) * NN) << 7) + c0;
    float s1[4] = {0.f, 0.f, 0.f, 0.f}, s2[4] = {0.f, 0.f, 0.f, 0.f};
    int rbase = w * 16;
    int cg = lane >> 2, wsel = lane & 3;
    // prologue: issue chunk-0 gathers
    u32 f[16];
#pragma unroll
    for (int j = 0; j < 16; ++j) {
        int id = __float_as_int(srel[rbase + j].w);
        f[j] = *(const u32*)(F1b + ((long)id << 7));
    }
    for (int c = 0; c < 8; ++c) {
        int m0 = m0b + c * 64;
        // consume chunk c: reconstruct act0(y0) rows, write swizzled LDS
#pragma unroll
        for (int j = 0; j < 16; ++j) {
            int r = rbase + j;
            float4 qv = srel[c * 64 + r];
            float2 ff = unpk2(f[j]);
            float v0 = fmaf(wx0, qv.x, fmaf(wy0, qv.y, fmaf(wz0, qv.z, ff.x)));
            float v1 = fmaf(wx1, qv.x, fmaf(wy1, qv.y, fmaf(wz1, qv.z, ff.y)));
            float a0 = fmaxf(fmaf(s4.x, v0, s4.y), 0.f);
            float a1 = fmaxf(fmaf(s4.z, v1, s4.w), 0.f);
            abuf[(r * 17 + ((cg + r) & 15)) * 4 + wsel] = packbf(a0, a1);
        }
        __syncthreads();
        // prefetch chunk c+1 (latency hides under MFMA + epilogue)
        if (c < 7) {
#pragma unroll
            for (int j = 0; j < 16; ++j) {
                int id = __float_as_int(srel[(c + 1) * 64 + rbase + j].w);
                f[j] = *(const u32*)(F1b + ((long)id << 7));
            }
        }
        f32x4 acc[2][4];
#pragma unroll
        for (int mt = 0; mt < 2; ++mt)
#pragma unroll
            for (int ct = 0; ct < 4; ++ct) acc[mt][ct] = (f32x4){0.f, 0.f, 0.f, 0.f};
        const uint4* ab4 = (const uint4*)abuf;
#pragma unroll
        for (int mt = 0; mt < 2; ++mt) {
            int row = wm0 + mt * 16 + l16;
#pragma unroll
            for (int k0 = 0; k0 < 4; ++k0) {
                uint4 v = ab4[row * 17 + ((k0 * 4 + q + row) & 15)];
                short8v af = as_s8(v);
#pragma unroll
                for (int ct = 0; ct < 4; ++ct)
                    acc[mt][ct] = MFMA16(af, bf[ct][k0], acc[mt][ct]);
            }
        }
#pragma unroll
        for (int mt = 0; mt < 2; ++mt)
#pragma unroll
            for (int ct = 0; ct < 4; ++ct)
#pragma unroll
                for (int r = 0; r < 4; ++r) {
                    float v = acc[mt][ct][r];
                    y[(long)(m0 + wm0 + mt * 16 + q * 4 + r) * 128 + cb + ct * 16 + l16] = f2b(v);
                    s1[ct] += v; s2[ct] = fmaf(v, v, s2[ct]);
                }
        __syncthreads();   // abuf consumed; safe to restage next chunk
    }
#pragma unroll
    for (int ct = 0; ct < 4; ++ct) {
        float a = s1[ct], b = s2[ct];
        a += __shfl_xor(a, 16); a += __shfl_xor(a, 32);
        b += __shfl_xor(b, 16); b += __shfl_xor(b, 32);
        if (lane < 16) { sredA[w][ct * 16 + l16] = a; sredB[w][ct * 16 + l16] = b; }
    }
    __syncthreads();
    if (t < 128) {
        int h = t >> 6, cl = t & 63;
        part [(long)t * NBLK + blockIdx.x] = sredA[h][cl] + sredA[h + 2][cl];
        partq[(long)t * NBLK + blockIdx.x] = sredB[h][cl] + sredB[h + 2][cl];
    }
}

// ---------------------------------------------------------------------------
// k_conv2pool: proven structure (B resident bf[4][4], wave = 64m x 64co,
// rotation swizzle, fused BN2 stat partials, 512 rows, grid 1024, 8 chunks)
// + r7 signed-extreme pooling: sign(sc2)=sign(g2) known pre-stats, store
// e = max over rows of (sgn*v) (== mx if g2>=0, == -mn if g2<0, exact).
// ---------------------------------------------------------------------------
__global__ __launch_bounds__(256) void k_conv2pool(const u16* __restrict__ y1,
                                                   const u16* __restrict__ w2b,
                                                   const float* __restrict__ st1,
                                                   const float* __restrict__ g2,
                                                   float* __restrict__ rawext,
                                                   float* __restrict__ part,
                                                   float* __restrict__ partq) {
    __shared__ uint4 abuf[2][64 * 17];
    __shared__ float2 sst[128];
    __shared__ float sredA[4][64], sredB[4][64];
    int t = threadIdx.x;
    if (t < 128) sst[t] = ((const float2*)st1)[t];
    int w = t >> 6, lane = t & 63, q = lane >> 4, l16 = lane & 15;
    int cb = w * 64;
    short8v bf[4][4];
#pragma unroll
    for (int ct = 0; ct < 4; ++ct)
#pragma unroll
        for (int k0 = 0; k0 < 4; ++k0)
            bf[ct][k0] = *(const short8v*)(w2b + (cb + ct * 16 + l16) * 128 + k0 * 32 + q * 8);
    // per-ct sign of g2 for this lane's output channels
    float sg[4];
#pragma unroll
    for (int ct = 0; ct < 4; ++ct)
        sg[ct] = g2[cb + ct * 16 + l16] >= 0.f ? 1.f : -1.f;
    __syncthreads();
    long m0b = (long)blockIdx.x * 512;
    int sr = t >> 4, sc16 = t & 15;
    float s1[4] = {0.f, 0.f, 0.f, 0.f}, s2[4] = {0.f, 0.f, 0.f, 0.f};
    for (int c = 0; c < 8; ++c) {
        long m0 = m0b + c * 64;
        uint4* ab = abuf[c & 1];
        const uint4* gsrc = (const uint4*)y1;
#pragma unroll
        for (int p = 0; p < 4; ++p) {
            int r = p * 16 + sr;
            uint4 d = gsrc[(m0 + r) * 16 + sc16];
            uint4 o;
            o.x = act_pack(d.x, sst[sc16 * 8 + 0], sst[sc16 * 8 + 1]);
            o.y = act_pack(d.y, sst[sc16 * 8 + 2], sst[sc16 * 8 + 3]);
            o.z = act_pack(d.z, sst[sc16 * 8 + 4], sst[sc16 * 8 + 5]);
            o.w = act_pack(d.w, sst[sc16 * 8 + 6], sst[sc16 * 8 + 7]);
            ab[r * 17 + ((sc16 + r) & 15)] = o;
        }
        __syncthreads();
        f32x4 acc[4][4];
#pragma unroll
        for (int mt = 0; mt < 4; ++mt)
#pragma unroll
            for (int ct = 0; ct < 4; ++ct) acc[mt][ct] = (f32x4){0.f, 0.f, 0.f, 0.f};
#pragma unroll
        for (int mt = 0; mt < 4; ++mt) {
            int row = mt * 16 + l16;
#pragma unroll
            for (int k0 = 0; k0 < 4; ++k0) {
                uint4 v = ab[row * 17 + ((k0 * 4 + q + row) & 15)];
                short8v af = as_s8(v);
#pragma unroll
                for (int ct = 0; ct < 4; ++ct)
                    acc[mt][ct] = MFMA16(af, bf[ct][k0], acc[mt][ct]);
            }
        }
        // pooling per 32-row group (mt pairs) + stats over all rows
#pragma unroll
        for (int ct = 0; ct < 4; ++ct) {
            float s = sg[ct];
#pragma unroll
            for (int g = 0; g < 2; ++g) {
                f32x4 a0 = acc[2 * g][ct], a1 = acc[2 * g + 1][ct];
                s1[ct] += a0[0] + a0[1] + a0[2] + a0[3] + a1[0] + a1[1] + a1[2] + a1[3];
                s2[ct] = fmaf(a0[0], a0[0], s2[ct]); s2[ct] = fmaf(a0[1], a0[1], s2[ct]);
                s2[ct] = fmaf(a0[2], a0[2], s2[ct]); s2[ct] = fmaf(a0[3], a0[3], s2[ct]);
                s2[ct] = fmaf(a1[0], a1[0], s2[ct]); s2[ct] = fmaf(a1[1], a1[1], s2[ct]);
                s2[ct] = fmaf(a1[2], a1[2], s2[ct]); s2[ct] = fmaf(a1[3], a1[3], s2[ct]);
                float e = fmaxf(fmaxf(fmaxf(s * a0[0], s * a0[1]), fmaxf(s * a0[2], s * a0[3])),
                                fmaxf(fmaxf(s * a1[0], s * a1[1]), fmaxf(s * a1[2], s * a1[3])));
                e = fmaxf(e, __shfl_xor(e, 16)); e = fmaxf(e, __shfl_xor(e, 32));
                if (lane < 16) {
                    long bp = (long)blockIdx.x * 16 + c * 2 + g;
                    rawext[bp * 256 + cb + ct * 16 + l16] = e;
                }
            }
        }
    }
#pragma unroll
    for (int ct = 0; ct < 4; ++ct) {
        float a = s1[ct], b = s2[ct];
        a += __shfl_xor(a, 16); a += __shfl_xor(a, 32);
        b += __shfl_xor(b, 16); b += __shfl_xor(b, 32);
        if (lane < 16) { sredA[w][ct * 16 + l16] = a; sredB[w][ct * 16 + l16] = b; }
    }
    __syncthreads();
    {
        part [(long)t * NBLK + blockIdx.x] = sredA[t >> 6][t & 63];
        partq[(long)t * NBLK + blockIdx.x] = sredB[t >> 6][t & 63];
    }
}

// ---------------------------------------------------------------------------
// k_final: e is the signed extreme (sgn*max(sgn*v)); recover the needed
// extreme exactly: x = sc>0 ? e : -e. z = relu(sc*x + sh); transpose to
// out[b][co][p].
// ---------------------------------------------------------------------------
__global__ void k_final(const float* __restrict__ rawext,
                        const float* __restrict__ st2, float* __restrict__ out) {
    __shared__ float tile[32][33];
    int b = blockIdx.x >> 8;
    int p0 = ((blockIdx.x >> 3) & 31) * 32;
    int c0 = (blockIdx.x & 7) * 32;
    int j = threadIdx.x & 31, i0 = threadIdx.x >> 5;
    float sc = st2[2 * (c0 + j)], sh = st2[2 * (c0 + j) + 1];
#pragma unroll
    for (int rr = 0; rr < 4; ++rr) {
        int i = i0 + rr * 8;
        long idx = ((long)(b * 1024 + p0 + i)) * 256 + c0 + j;
        float e = rawext[idx];
        float x = sc > 0.f ? e : -e;
        tile[i][j] = fmaxf(fmaf(sc, x, sh), 0.f);
    }
    __syncthreads();
#pragma unroll
    for (int rr = 0; rr < 4; ++rr) {
        int i = i0 + rr * 8;
        out[OFF_NF + (long)b * 262144 + (c0 + i) * 1024 + p0 + j] = tile[j][i];
    }
}

// ---------------------------------------------------------------------------
extern "C" void kernel_launch(void* const* d_in, const int* in_sizes, int n_in,
                              void* d_out, int out_size, void* d_ws, size_t ws_size,
                              hipStream_t stream) {
    (void)in_sizes; (void)n_in; (void)out_size; (void)ws_size;
    const float* xyz  = (const float*)d_in[0];
    const float* feat = (const float*)d_in[1];
    const float* w0   = (const float*)d_in[3];
    const float* g0   = (const float*)d_in[5];
    const float* be0  = (const float*)d_in[6];
    const float* w1   = (const float*)d_in[7];
    const float* g1   = (const float*)d_in[9];
    const float* be1  = (const float*)d_in[10];
    const float* w2   = (const float*)d_in[11];
    const float* g2   = (const float*)d_in[13];
    const float* be2  = (const float*)d_in[14];
    float* out = (float*)d_out;

    char* ws = (char*)d_ws;
    size_t off = 0;
    auto alloc = [&](size_t bytes) -> void* {
        void* p = ws + off;
        off = (off + bytes + 4095) & ~(size_t)4095;
        return p;
    };
    float4* rel4  = (float4*)alloc((size_t)MM * 16);          // 8 MB
    float* w0t    = (float*)alloc(3 * 128 * 4);
    u16*   w0b    = (u16*)  alloc(128 * 128 * 2);
    u16*   w1b    = (u16*)  alloc(128 * 128 * 2);
    u16*   w2b    = (u16*)  alloc(256 * 128 * 2);
    float* st0    = (float*)alloc(128 * 2 * 4);
    float* st1    = (float*)alloc(128 * 2 * 4);
    float* st2    = (float*)alloc(256 * 2 * 4);
    float* part   = (float*)alloc((size_t)256 * NBLK * 4);    // 8 MB
    float* partq  = (float*)alloc((size_t)256 * NBLK * 4);    // 8 MB
    u16*   F1     = (u16*)  alloc((size_t)BB * NN * 128 * 2); // 16.8 MB (bf16)
    float* rawext = (float*)alloc((size_t)BB * PP * 256 * 4); // 16 MB
    u16*   bufA   = (u16*)  alloc((size_t)MM * 128 * 2);      // 134 MB (y1)

    k_init<<<514, 256, 0, stream>>>(xyz, w0, w1, w2, out, w0t, w0b, w1b, w2b);
    k_bqf1<<<2048, 256, 0, stream>>>(xyz, feat, w0b, rel4, F1);
    k_y0stats<<<2048, 256, 0, stream>>>(rel4, w0t, F1, part, partq);
    k_bnfin<<<128, 256, 0, stream>>>(part, partq, g0, be0, st0, 2048);
    k_conv1<<<1024, 256, 0, stream>>>(rel4, F1, w1b, w0t, st0, bufA, part, partq);
    k_bnfin<<<128, 256, 0, stream>>>(part, partq, g1, be1, st1, 1024);
    k_conv2pool<<<1024, 256, 0, stream>>>(bufA, w2b, st1, g2, rawext, part, partq);
    k_bnfin<<<256, 256, 0, stream>>>(part, partq, g2, be2, st2, 1024);
    k_final<<<4096, 256, 0, stream>>>(rawext, st2, out);
}

// Round 11
// 291.172 us; speedup vs baseline: 1.3089x; 1.3089x over previous
//
#include <hip/hip_runtime.h>

#define BB 16
#define NN 4096
#define CC 128
#define PP 1024
#define SS 32
#define MM (BB*PP*SS)       // 524288
#define NBLK 8192           // stat-partial stride
#define OFF_NF 49152        // 16*1024*3
#define OFF_SI 4243456      // 49152 + 16*256*1024

typedef unsigned short u16;
typedef unsigned int u32;
typedef __attribute__((ext_vector_type(8))) short short8v;
typedef __attribute__((ext_vector_type(4))) float f32x4;

__device__ __forceinline__ float b2f(u16 u) {
    union { float f; unsigned i; } x; x.i = ((unsigned)u) << 16; return x.f;
}
__device__ __forceinline__ u16 f2b(float f) {   // RTNE bf16
    union { float f; unsigned i; } x; x.f = f;
    unsigned r = x.i + 0x7fffu + ((x.i >> 16) & 1u);
    return (u16)(r >> 16);
}
__device__ __forceinline__ float2 act2(u32 u, float2 s0, float2 s1) {
    union { float f; unsigned i; } a, b;
    a.i = u << 16; b.i = u & 0xffff0000u;
    return make_float2(fmaxf(fmaf(s0.x, a.f, s0.y), 0.f),
                       fmaxf(fmaf(s1.x, b.f, s1.y), 0.f));
}
// unpack 2 bf16 (lo, hi) from one u32
__device__ __forceinline__ float2 unpk2(u32 u) {
    union { float f; unsigned i; } a, b;
    a.i = u << 16; b.i = u & 0xffff0000u;
    return make_float2(a.f, b.f);
}
__device__ __forceinline__ u32 packbf(float flo, float fhi) {
    union { float f; unsigned i; } x0, x1; x0.f = flo; x1.f = fhi;
    return __builtin_amdgcn_perm(x1.i, x0.i, 0x07060302u);
}
__device__ __forceinline__ u32 packbf_rtne(float flo, float fhi) {
    union { float f; unsigned i; } x0, x1; x0.f = flo; x1.f = fhi;
    u32 r0 = x0.i + 0x7fffu + ((x0.i >> 16) & 1u);
    u32 r1 = x1.i + 0x7fffu + ((x1.i >> 16) & 1u);
    return __builtin_amdgcn_perm(r1, r0, 0x07060302u);
}
__device__ __forceinline__ u32 act_pack(u32 u, float2 s0, float2 s1) {
    float2 f = act2(u, s0, s1);
    return packbf(f.x, f.y);
}
__device__ __forceinline__ short8v as_s8(uint4 v) {
    union { uint4 u; short8v s; } x; x.u = v; return x.s;
}

#define MFMA16(a,b,c) __builtin_amdgcn_mfma_f32_16x16x32_bf16(a,b,c,0,0,0)

// ---------------------------------------------------------------------------
// k_init: new_xyz + sample_idxs + w0t (xyz rows, fp32) + w0b/w1b/w2b (bf16)
// ---------------------------------------------------------------------------
__global__ void k_init(const float* __restrict__ xyz, const float* __restrict__ w0,
                       const float* __restrict__ w1, const float* __restrict__ w2,
                       float* __restrict__ out, float* __restrict__ w0t,
                       u16* __restrict__ w0b, u16* __restrict__ w1b,
                       u16* __restrict__ w2b) {
    int i = blockIdx.x * 256 + threadIdx.x;
    if (i < 49152) {
        int b = i / 3072, r = i % 3072;
        out[i] = xyz[b * 12288 + r];
        return;
    }
    int j = i - 49152;
    if (j < 16384) { out[OFF_SI + j] = (float)(j & 1023); return; }
    int e = j - 16384;
    if (e < 384) { w0t[e] = w0[(e & 127) * 131 + (e >> 7)]; return; }
    int f = e - 384;
    if (f < 16384) { w0b[f] = f2b(w0[(f >> 7) * 131 + 3 + (f & 127)]); return; }
    int h = f - 16384;
    if (h < 16384) { w1b[h] = f2b(w1[h]); return; }
    int k2 = h - 16384;
    if (k2 < 32768) { w2b[k2] = f2b(w2[k2]); }
}

// ---------------------------------------------------------------------------
// k_bqf1: FUSED ballquery + f1. 16 centers per bq block (wave scans 4 from
// one staged 48KB xyz tile). Grid 2048: even = f1 tile, odd = bq block.
// LDS = 48KB union (bq sx/sy/sz >= f1 abuf 17408 B).
// ---------------------------------------------------------------------------
__global__ __launch_bounds__(256) void k_bqf1(const float* __restrict__ xyz,
                                              const float* __restrict__ feat,
                                              const u16* __restrict__ w0b,
                                              float4* __restrict__ rel4,
                                              u16* __restrict__ F1) {
    __shared__ __align__(16) float smem[12288];   // 48 KB union
    int bid = blockIdx.x;
    int q2 = bid >> 1;
    int t = threadIdx.x;
    if (!(bid & 1)) {
        // ---------------- f1 tile q2: F1[n][co] = feat . w0b -------------
        uint4* abuf = (uint4*)smem;               // 64*17 uint4 = 17408 B
        int fb = q2;
        int w = t >> 6, lane = t & 63, q = lane >> 4, l16 = lane & 15;
        int cb = (w & 1) * 64, wm0 = (w >> 1) * 32;
        short8v bf[4][4];
#pragma unroll
        for (int ct = 0; ct < 4; ++ct)
#pragma unroll
            for (int k0 = 0; k0 < 4; ++k0)
                bf[ct][k0] = *(const short8v*)(w0b + (cb + ct * 16 + l16) * 128 + k0 * 32 + q * 8);
        int nl = t & 63, cg = t >> 6;
        const float* fcol = feat + (long)(fb >> 6) * (128 * 4096)
                                 + (long)(fb & 63) * 64 + nl;
#pragma unroll
        for (int pp = 0; pp < 4; ++pp) {
            int oct = cg + 4 * pp;
            float v[8];
#pragma unroll
            for (int r = 0; r < 8; ++r) v[r] = fcol[(long)(oct * 8 + r) * 4096];
            uint4 ov;
            ov.x = packbf_rtne(v[0], v[1]); ov.y = packbf_rtne(v[2], v[3]);
            ov.z = packbf_rtne(v[4], v[5]); ov.w = packbf_rtne(v[6], v[7]);
            abuf[nl * 17 + ((oct + nl) & 15)] = ov;
        }
        __syncthreads();
        f32x4 acc[2][4];
#pragma unroll
        for (int mt = 0; mt < 2; ++mt)
#pragma unroll
            for (int ct = 0; ct < 4; ++ct) acc[mt][ct] = (f32x4){0.f, 0.f, 0.f, 0.f};
#pragma unroll
        for (int mt = 0; mt < 2; ++mt) {
            int row = wm0 + mt * 16 + l16;
#pragma unroll
            for (int k0 = 0; k0 < 4; ++k0) {
                uint4 vv = abuf[row * 17 + ((k0 * 4 + q + row) & 15)];
                short8v af = as_s8(vv);
#pragma unroll
                for (int ct = 0; ct < 4; ++ct)
                    acc[mt][ct] = MFMA16(af, bf[ct][k0], acc[mt][ct]);
            }
        }
        long nbase = (long)fb * 64;
#pragma unroll
        for (int mt = 0; mt < 2; ++mt)
#pragma unroll
            for (int ct = 0; ct < 4; ++ct)
#pragma unroll
                for (int r = 0; r < 4; ++r)
                    F1[(nbase + wm0 + mt * 16 + q * 4 + r) * 128 + cb + ct * 16 + l16]
                        = f2b(acc[mt][ct][r]);
    } else {
        // -------- ballquery block q2: 16 centers, wave w scans 4 --------
        float* sx = smem;
        float* sy = smem + 4096;
        float* sz = smem + 8192;
        int w = t >> 6, lane = t & 63;
        int b = q2 >> 6;                   // 64 bq blocks per batch
        int pbase = (q2 & 63) * 16;
        const float* xb = xyz + (long)b * NN * 3;
        for (int i = t; i < NN; i += 256) {
            sx[i] = xb[3 * i]; sy[i] = xb[3 * i + 1]; sz[i] = xb[3 * i + 2];
        }
        __syncthreads();
        const float R2 = (float)(0.4 * 0.4);
#pragma unroll 1
        for (int k = 0; k < 4; ++k) {
            int p = pbase + 4 * w + k;
            float cx = sx[p], cy = sy[p], cz = sz[p];
            int o = (b * PP + p) * SS;
            int cnt = 0, firstn = 0;
            float fdx = 0.f, fdy = 0.f, fdz = 0.f;
            for (int c = 0; c < 64 && cnt < 32; ++c) {
                int n = c * 64 + lane;
                float dx = __fsub_rn(sx[n], cx);
                float dy = __fsub_rn(sy[n], cy);
                float dz = __fsub_rn(sz[n], cz);
                float d2 = __fadd_rn(__fadd_rn(__fmul_rn(dx, dx), __fmul_rn(dy, dy)),
                                     __fmul_rn(dz, dz));
                bool hit = d2 < R2;
                unsigned long long mask = __ballot(hit);
                if (mask) {
                    if (cnt == 0) {
                        int fl = __ffsll(mask) - 1;
                        firstn = c * 64 + fl;
                        fdx = __shfl(dx, fl); fdy = __shfl(dy, fl); fdz = __shfl(dz, fl);
                    }
                    int pos = cnt + __popcll(mask & ((1ull << lane) - 1ull));
                    if (hit && pos < 32) {
                        rel4[o + pos] = make_float4(dx, dy, dz, __int_as_float(n));
                    }
                    cnt += __popcll(mask);
                }
            }
            if (lane < 32 && lane >= cnt) {
                rel4[o + lane] = make_float4(fdx, fdy, fdz, __int_as_float(firstn));
            }
        }
    }
}

// ---------------------------------------------------------------------------
// k_y0stats: BN0 partials without materializing y0. rel4 staged to LDS;
// F1 (bf16) gathers batched 16-deep with one-group-ahead prefetch.
// ---------------------------------------------------------------------------
__global__ __launch_bounds__(256) void k_y0stats(const float4* __restrict__ rel4,
                                                 const float* __restrict__ w0t,
                                                 const u16* __restrict__ F1,
                                                 float* __restrict__ part,
                                                 float* __restrict__ partq) {
    __shared__ float4 srel[256];
    int t = threadIdx.x, w = t >> 6, lane = t & 63;
    int c0 = 2 * lane;
    float wx0 = w0t[c0],       wx1 = w0t[c0 + 1];
    float wy0 = w0t[128 + c0], wy1 = w0t[128 + c0 + 1];
    float wz0 = w0t[256 + c0], wz1 = w0t[256 + c0 + 1];
    int m0 = blockIdx.x * 256;
    srel[t] = rel4[m0 + t];
    __syncthreads();
    // whole block shares one batch b (256 | 32768)
    const u16* F1b = F1 + (((long)(blockIdx.x >> 7) * NN) << 7) + c0;
    float s1a = 0.f, s1b = 0.f, s2a = 0.f, s2b = 0.f;
    u32 f[16];
#pragma unroll
    for (int j = 0; j < 16; ++j) {
        int id = __float_as_int(srel[w + 4 * j].w);
        f[j] = *(const u32*)(F1b + ((long)id << 7));
    }
#pragma unroll
    for (int g = 0; g < 4; ++g) {
        u32 fn[16];
        if (g < 3) {
#pragma unroll
            for (int j = 0; j < 16; ++j) {
                int id = __float_as_int(srel[w + 4 * (16 * (g + 1) + j)].w);
                fn[j] = *(const u32*)(F1b + ((long)id << 7));
            }
        }
#pragma unroll
        for (int j = 0; j < 16; ++j) {
            float4 qv = srel[w + 4 * (16 * g + j)];
            float2 ff = unpk2(f[j]);
            float v0 = fmaf(wx0, qv.x, fmaf(wy0, qv.y, fmaf(wz0, qv.z, ff.x)));
            float v1 = fmaf(wx1, qv.x, fmaf(wy1, qv.y, fmaf(wz1, qv.z, ff.y)));
            s1a += v0; s2a = fmaf(v0, v0, s2a);
            s1b += v1; s2b = fmaf(v1, v1, s2b);
        }
#pragma unroll
        for (int j = 0; j < 16; ++j) f[j] = fn[j];
    }
    __shared__ float r1[128][4], r2[128][4];
    r1[c0][w] = s1a; r1[c0 + 1][w] = s1b;
    r2[c0][w] = s2a; r2[c0 + 1][w] = s2b;
    __syncthreads();
    if (t < 128) {
        float a1 = r1[t][0] + r1[t][1] + r1[t][2] + r1[t][3];
        float a2 = r2[t][0] + r2[t][1] + r2[t][2] + r2[t][3];
        part [(long)t * NBLK + blockIdx.x] = a1;
        partq[(long)t * NBLK + blockIdx.x] = a2;
    }
}

// ---------------------------------------------------------------------------
// k_bnfin: reduce per-channel partials -> (scale, shift). grid = #channels.
// ---------------------------------------------------------------------------
__global__ void k_bnfin(const float* __restrict__ part, const float* __restrict__ partq,
                        const float* __restrict__ g, const float* __restrict__ beta,
                        float* __restrict__ st, int nblk) {
    int co = blockIdx.x, t = threadIdx.x;
    const float* p1 = part + (long)co * NBLK;
    const float* p2 = partq + (long)co * NBLK;
    float s1 = 0.f, s2 = 0.f;
    for (int j = t; j < nblk; j += 256) { s1 += p1[j]; s2 += p2[j]; }
    __shared__ float r1[256], r2[256];
    r1[t] = s1; r2[t] = s2; __syncthreads();
    for (int off = 128; off > 0; off >>= 1) {
        if (t < off) { r1[t] += r1[t + off]; r2[t] += r2[t + off]; }
        __syncthreads();
    }
    if (t == 0) {
        const float inv = 1.f / (float)MM;
        float mean = r1[0] * inv;
        float var = r2[0] * inv - mean * mean;
        float sc = g[co] * rsqrtf(var + 1e-5f);
        st[2 * co] = sc;
        st[2 * co + 1] = fmaf(-mean, sc, beta[co]);
    }
}

// ---------------------------------------------------------------------------
// k_conv1: y1 = W1 . act0(y0), act0(y0) reconstructed in staging from
// srel (LDS copy of rel4) + F1 (bf16) gather + st0. r7/r9-PROVEN config:
// 512 rows, grid 1024, 8 chunks, double-buffered stride-17 abuf,
// launch_bounds(256,3), 45056 B LDS. LOCKED: launch_bounds >3 spills
// (r6: cap 64, r10: cap 48 -> FETCH 320-346 MB scratch). Stride-16
// breaks swizzle (r6: 1M conflicts). THIS ROUND: paired u32 y1 stores
// (shfl_xor lane pairing, even lanes store 2 cols) -- halves store
// instructions, 64B contiguous per 16-lane group (was 32B partial
// sectors; WRITE_SIZE 150 vs 134 logical).
// ---------------------------------------------------------------------------
__global__ __launch_bounds__(256, 3) void k_conv1(const float4* __restrict__ rel4,
                                                  const u16* __restrict__ F1,
                                                  const u16* __restrict__ w1b,
                                                  const float* __restrict__ w0t,
                                                  const float* __restrict__ st0,
                                                  u16* __restrict__ y,
                                                  float* __restrict__ part,
                                                  float* __restrict__ partq) {
    __shared__ u32 abuf[2][64 * 17 * 4];
    __shared__ float4 srel[512];
    __shared__ float sredA[4][64], sredB[4][64];
    int t = threadIdx.x;
    int w = t >> 6, lane = t & 63, q = lane >> 4, l16 = lane & 15;
    int wm0 = (w >> 1) * 32, cb = (w & 1) * 64;
    short8v bf[4][4];
#pragma unroll
    for (int ct = 0; ct < 4; ++ct)
#pragma unroll
        for (int k0 = 0; k0 < 4; ++k0)
            bf[ct][k0] = *(const short8v*)(w1b + (cb + ct * 16 + l16) * 128 + k0 * 32 + q * 8);
    // staging constants for cols (2*lane, 2*lane+1)
    int c0 = 2 * lane;
    float wx0 = w0t[c0],       wx1 = w0t[c0 + 1];
    float wy0 = w0t[128 + c0], wy1 = w0t[128 + c0 + 1];
    float wz0 = w0t[256 + c0], wz1 = w0t[256 + c0 + 1];
    float4 s4 = *(const float4*)(st0 + 2 * c0);   // sc0, sh0, sc1, sh1
    int m0b = blockIdx.x * 512;
    // stage rel4 for the whole block into LDS (coalesced, once)
    srel[t] = rel4[m0b + t];
    srel[t + 256] = rel4[m0b + t + 256];
    __syncthreads();
    // whole block shares one batch b (512 | 32768)
    const u16* F1b = F1 + (((long)(blockIdx.x >> 6) * NN) << 7) + c0;
    float s1[4] = {0.f, 0.f, 0.f, 0.f}, s2[4] = {0.f, 0.f, 0.f, 0.f};
    int rbase = w * 16;
    int cg = lane >> 2, wsel = lane & 3;
    u32* yo = (u32*)y;
    // prologue: issue chunk-0 gathers
    u32 f[16];
#pragma unroll
    for (int j = 0; j < 16; ++j) {
        int id = __float_as_int(srel[rbase + j].w);
        f[j] = *(const u32*)(F1b + ((long)id << 7));
    }
    for (int c = 0; c < 8; ++c) {
        int m0 = m0b + c * 64;
        u32* ab = abuf[c & 1];
        // consume chunk c: reconstruct act0(y0) rows, write swizzled LDS
#pragma unroll
        for (int j = 0; j < 16; ++j) {
            int r = rbase + j;
            float4 qv = srel[c * 64 + r];
            float2 ff = unpk2(f[j]);
            float v0 = fmaf(wx0, qv.x, fmaf(wy0, qv.y, fmaf(wz0, qv.z, ff.x)));
            float v1 = fmaf(wx1, qv.x, fmaf(wy1, qv.y, fmaf(wz1, qv.z, ff.y)));
            float a0 = fmaxf(fmaf(s4.x, v0, s4.y), 0.f);
            float a1 = fmaxf(fmaf(s4.z, v1, s4.w), 0.f);
            ab[(r * 17 + ((cg + r) & 15)) * 4 + wsel] = packbf(a0, a1);
        }
        __syncthreads();
        // prefetch chunk c+1 (latency hides under MFMA + epilogue)
        if (c < 7) {
#pragma unroll
            for (int j = 0; j < 16; ++j) {
                int id = __float_as_int(srel[(c + 1) * 64 + rbase + j].w);
                f[j] = *(const u32*)(F1b + ((long)id << 7));
            }
        }
        f32x4 acc[2][4];
#pragma unroll
        for (int mt = 0; mt < 2; ++mt)
#pragma unroll
            for (int ct = 0; ct < 4; ++ct) acc[mt][ct] = (f32x4){0.f, 0.f, 0.f, 0.f};
        const uint4* ab4 = (const uint4*)ab;
#pragma unroll
        for (int mt = 0; mt < 2; ++mt) {
            int row = wm0 + mt * 16 + l16;
#pragma unroll
            for (int k0 = 0; k0 < 4; ++k0) {
                uint4 v = ab4[row * 17 + ((k0 * 4 + q + row) & 15)];
                short8v af = as_s8(v);
#pragma unroll
                for (int ct = 0; ct < 4; ++ct)
                    acc[mt][ct] = MFMA16(af, bf[ct][k0], acc[mt][ct]);
            }
        }
        // epilogue: stats + paired u32 y1 stores (cols l16 even, l16^1)
#pragma unroll
        for (int mt = 0; mt < 2; ++mt)
#pragma unroll
            for (int ct = 0; ct < 4; ++ct)
#pragma unroll
                for (int r = 0; r < 4; ++r) {
                    float v = acc[mt][ct][r];
                    s1[ct] += v; s2[ct] = fmaf(v, v, s2[ct]);
                    float vp = __shfl_xor(v, 1);
                    if (!(lane & 1))
                        yo[(long)(m0 + wm0 + mt * 16 + q * 4 + r) * 64
                           + ((cb + ct * 16 + l16) >> 1)] = packbf_rtne(v, vp);
                }
    }
#pragma unroll
    for (int ct = 0; ct < 4; ++ct) {
        float a = s1[ct], b = s2[ct];
        a += __shfl_xor(a, 16); a += __shfl_xor(a, 32);
        b += __shfl_xor(b, 16); b += __shfl_xor(b, 32);
        if (lane < 16) { sredA[w][ct * 16 + l16] = a; sredB[w][ct * 16 + l16] = b; }
    }
    __syncthreads();
    if (t < 128) {
        int h = t >> 6, cl = t & 63;
        part [(long)t * NBLK + blockIdx.x] = sredA[h][cl] + sredA[h + 2][cl];
        partq[(long)t * NBLK + blockIdx.x] = sredB[h][cl] + sredB[h + 2][cl];
    }
}

// ---------------------------------------------------------------------------
// k_conv2pool: proven structure (B resident bf[4][4], wave = 64m x 64co,
// rotation swizzle, fused BN2 stat partials, 512 rows, grid 1024, 8 chunks)
// + r7 signed-extreme pooling: sign(sc2)=sign(g2) known pre-stats, store
// e = max over rows of (sgn*v) (== mx if g2>=0, == -mn if g2<0, exact).
// ---------------------------------------------------------------------------
__global__ __launch_bounds__(256) void k_conv2pool(const u16* __restrict__ y1,
                                                   const u16* __restrict__ w2b,
                                                   const float* __restrict__ st1,
                                                   const float* __restrict__ g2,
                                                   float* __restrict__ rawext,
                                                   float* __restrict__ part,
                                                   float* __restrict__ partq) {
    __shared__ uint4 abuf[2][64 * 17];
    __shared__ float2 sst[128];
    __shared__ float sredA[4][64], sredB[4][64];
    int t = threadIdx.x;
    if (t < 128) sst[t] = ((const float2*)st1)[t];
    int w = t >> 6, lane = t & 63, q = lane >> 4, l16 = lane & 15;
    int cb = w * 64;
    short8v bf[4][4];
#pragma unroll
    for (int ct = 0; ct < 4; ++ct)
#pragma unroll
        for (int k0 = 0; k0 < 4; ++k0)
            bf[ct][k0] = *(const short8v*)(w2b + (cb + ct * 16 + l16) * 128 + k0 * 32 + q * 8);
    // per-ct sign of g2 for this lane's output channels
    float sg[4];
#pragma unroll
    for (int ct = 0; ct < 4; ++ct)
        sg[ct] = g2[cb + ct * 16 + l16] >= 0.f ? 1.f : -1.f;
    __syncthreads();
    long m0b = (long)blockIdx.x * 512;
    int sr = t >> 4, sc16 = t & 15;
    float s1[4] = {0.f, 0.f, 0.f, 0.f}, s2[4] = {0.f, 0.f, 0.f, 0.f};
    for (int c = 0; c < 8; ++c) {
        long m0 = m0b + c * 64;
        uint4* ab = abuf[c & 1];
        const uint4* gsrc = (const uint4*)y1;
#pragma unroll
        for (int p = 0; p < 4; ++p) {
            int r = p * 16 + sr;
            uint4 d = gsrc[(m0 + r) * 16 + sc16];
            uint4 o;
            o.x = act_pack(d.x, sst[sc16 * 8 + 0], sst[sc16 * 8 + 1]);
            o.y = act_pack(d.y, sst[sc16 * 8 + 2], sst[sc16 * 8 + 3]);
            o.z = act_pack(d.z, sst[sc16 * 8 + 4], sst[sc16 * 8 + 5]);
            o.w = act_pack(d.w, sst[sc16 * 8 + 6], sst[sc16 * 8 + 7]);
            ab[r * 17 + ((sc16 + r) & 15)] = o;
        }
        __syncthreads();
        f32x4 acc[4][4];
#pragma unroll
        for (int mt = 0; mt < 4; ++mt)
#pragma unroll
            for (int ct = 0; ct < 4; ++ct) acc[mt][ct] = (f32x4){0.f, 0.f, 0.f, 0.f};
#pragma unroll
        for (int mt = 0; mt < 4; ++mt) {
            int row = mt * 16 + l16;
#pragma unroll
            for (int k0 = 0; k0 < 4; ++k0) {
                uint4 v = ab[row * 17 + ((k0 * 4 + q + row) & 15)];
                short8v af = as_s8(v);
#pragma unroll
                for (int ct = 0; ct < 4; ++ct)
                    acc[mt][ct] = MFMA16(af, bf[ct][k0], acc[mt][ct]);
            }
        }
        // pooling per 32-row group (mt pairs) + stats over all rows
#pragma unroll
        for (int ct = 0; ct < 4; ++ct) {
            float s = sg[ct];
#pragma unroll
            for (int g = 0; g < 2; ++g) {
                f32x4 a0 = acc[2 * g][ct], a1 = acc[2 * g + 1][ct];
                s1[ct] += a0[0] + a0[1] + a0[2] + a0[3] + a1[0] + a1[1] + a1[2] + a1[3];
                s2[ct] = fmaf(a0[0], a0[0], s2[ct]); s2[ct] = fmaf(a0[1], a0[1], s2[ct]);
                s2[ct] = fmaf(a0[2], a0[2], s2[ct]); s2[ct] = fmaf(a0[3], a0[3], s2[ct]);
                s2[ct] = fmaf(a1[0], a1[0], s2[ct]); s2[ct] = fmaf(a1[1], a1[1], s2[ct]);
                s2[ct] = fmaf(a1[2], a1[2], s2[ct]); s2[ct] = fmaf(a1[3], a1[3], s2[ct]);
                float e = fmaxf(fmaxf(fmaxf(s * a0[0], s * a0[1]), fmaxf(s * a0[2], s * a0[3])),
                                fmaxf(fmaxf(s * a1[0], s * a1[1]), fmaxf(s * a1[2], s * a1[3])));
                e = fmaxf(e, __shfl_xor(e, 16)); e = fmaxf(e, __shfl_xor(e, 32));
                if (lane < 16) {
                    long bp = (long)blockIdx.x * 16 + c * 2 + g;
                    rawext[bp * 256 + cb + ct * 16 + l16] = e;
                }
            }
        }
    }
#pragma unroll
    for (int ct = 0; ct < 4; ++ct) {
        float a = s1[ct], b = s2[ct];
        a += __shfl_xor(a, 16); a += __shfl_xor(a, 32);
        b += __shfl_xor(b, 16); b += __shfl_xor(b, 32);
        if (lane < 16) { sredA[w][ct * 16 + l16] = a; sredB[w][ct * 16 + l16] = b; }
    }
    __syncthreads();
    {
        part [(long)t * NBLK + blockIdx.x] = sredA[t >> 6][t & 63];
        partq[(long)t * NBLK + blockIdx.x] = sredB[t >> 6][t & 63];
    }
}

// ---------------------------------------------------------------------------
// k_final: e is the signed extreme (sgn*max(sgn*v)); recover the needed
// extreme exactly: x = sc>0 ? e : -e. z = relu(sc*x + sh); transpose to
// out[b][co][p].
// ---------------------------------------------------------------------------
__global__ void k_final(const float* __restrict__ rawext,
                        const float* __restrict__ st2, float* __restrict__ out) {
    __shared__ float tile[32][33];
    int b = blockIdx.x >> 8;
    int p0 = ((blockIdx.x >> 3) & 31) * 32;
    int c0 = (blockIdx.x & 7) * 32;
    int j = threadIdx.x & 31, i0 = threadIdx.x >> 5;
    float sc = st2[2 * (c0 + j)], sh = st2[2 * (c0 + j) + 1];
#pragma unroll
    for (int rr = 0; rr < 4; ++rr) {
        int i = i0 + rr * 8;
        long idx = ((long)(b * 1024 + p0 + i)) * 256 + c0 + j;
        float e = rawext[idx];
        float x = sc > 0.f ? e : -e;
        tile[i][j] = fmaxf(fmaf(sc, x, sh), 0.f);
    }
    __syncthreads();
#pragma unroll
    for (int rr = 0; rr < 4; ++rr) {
        int i = i0 + rr * 8;
        out[OFF_NF + (long)b * 262144 + (c0 + i) * 1024 + p0 + j] = tile[j][i];
    }
}

// ---------------------------------------------------------------------------
extern "C" void kernel_launch(void* const* d_in, const int* in_sizes, int n_in,
                              void* d_out, int out_size, void* d_ws, size_t ws_size,
                              hipStream_t stream) {
    (void)in_sizes; (void)n_in; (void)out_size; (void)ws_size;
    const float* xyz  = (const float*)d_in[0];
    const float* feat = (const float*)d_in[1];
    const float* w0   = (const float*)d_in[3];
    const float* g0   = (const float*)d_in[5];
    const float* be0  = (const float*)d_in[6];
    const float* w1   = (const float*)d_in[7];
    const float* g1   = (const float*)d_in[9];
    const float* be1  = (const float*)d_in[10];
    const float* w2   = (const float*)d_in[11];
    const float* g2   = (const float*)d_in[13];
    const float* be2  = (const float*)d_in[14];
    float* out = (float*)d_out;

    char* ws = (char*)d_ws;
    size_t off = 0;
    auto alloc = [&](size_t bytes) -> void* {
        void* p = ws + off;
        off = (off + bytes + 4095) & ~(size_t)4095;
        return p;
    };
    float4* rel4  = (float4*)alloc((size_t)MM * 16);          // 8 MB
    float* w0t    = (float*)alloc(3 * 128 * 4);
    u16*   w0b    = (u16*)  alloc(128 * 128 * 2);
    u16*   w1b    = (u16*)  alloc(128 * 128 * 2);
    u16*   w2b    = (u16*)  alloc(256 * 128 * 2);
    float* st0    = (float*)alloc(128 * 2 * 4);
    float* st1    = (float*)alloc(128 * 2 * 4);
    float* st2    = (float*)alloc(256 * 2 * 4);
    float* part   = (float*)alloc((size_t)256 * NBLK * 4);    // 8 MB
    float* partq  = (float*)alloc((size_t)256 * NBLK * 4);    // 8 MB
    u16*   F1     = (u16*)  alloc((size_t)BB * NN * 128 * 2); // 16.8 MB (bf16)
    float* rawext = (float*)alloc((size_t)BB * PP * 256 * 4); // 16 MB
    u16*   bufA   = (u16*)  alloc((size_t)MM * 128 * 2);      // 134 MB (y1)

    k_init<<<514, 256, 0, stream>>>(xyz, w0, w1, w2, out, w0t, w0b, w1b, w2b);
    k_bqf1<<<2048, 256, 0, stream>>>(xyz, feat, w0b, rel4, F1);
    k_y0stats<<<2048, 256, 0, stream>>>(rel4, w0t, F1, part, partq);
    k_bnfin<<<128, 256, 0, stream>>>(part, partq, g0, be0, st0, 2048);
    k_conv1<<<1024, 256, 0, stream>>>(rel4, F1, w1b, w0t, st0, bufA, part, partq);
    k_bnfin<<<128, 256, 0, stream>>>(part, partq, g1, be1, st1, 1024);
    k_conv2pool<<<1024, 256, 0, stream>>>(bufA, w2b, st1, g2, rawext, part, partq);
    k_bnfin<<<256, 256, 0, stream>>>(part, partq, g2, be2, st2, 1024);
    k_final<<<4096, 256, 0, stream>>>(rawext, st2, out);
}

// Round 12
// 276.624 us; speedup vs baseline: 1.3777x; 1.0526x over previous
//
#include <hip/hip_runtime.h>

#define BB 16
#define NN 4096
#define CC 128
#define PP 1024
#define SS 32
#define MM (BB*PP*SS)       // 524288
#define NBLK 8192           // stat-partial stride
#define OFF_NF 49152        // 16*1024*3
#define OFF_SI 4243456      // 49152 + 16*256*1024

typedef unsigned short u16;
typedef unsigned int u32;
typedef __attribute__((ext_vector_type(8))) short short8v;
typedef __attribute__((ext_vector_type(4))) float f32x4;

__device__ __forceinline__ float b2f(u16 u) {
    union { float f; unsigned i; } x; x.i = ((unsigned)u) << 16; return x.f;
}
__device__ __forceinline__ u16 f2b(float f) {   // RTNE bf16
    union { float f; unsigned i; } x; x.f = f;
    unsigned r = x.i + 0x7fffu + ((x.i >> 16) & 1u);
    return (u16)(r >> 16);
}
__device__ __forceinline__ float2 act2(u32 u, float2 s0, float2 s1) {
    union { float f; unsigned i; } a, b;
    a.i = u << 16; b.i = u & 0xffff0000u;
    return make_float2(fmaxf(fmaf(s0.x, a.f, s0.y), 0.f),
                       fmaxf(fmaf(s1.x, b.f, s1.y), 0.f));
}
// unpack 2 bf16 (lo, hi) from one u32
__device__ __forceinline__ float2 unpk2(u32 u) {
    union { float f; unsigned i; } a, b;
    a.i = u << 16; b.i = u & 0xffff0000u;
    return make_float2(a.f, b.f);
}
__device__ __forceinline__ u32 packbf(float flo, float fhi) {
    union { float f; unsigned i; } x0, x1; x0.f = flo; x1.f = fhi;
    return __builtin_amdgcn_perm(x1.i, x0.i, 0x07060302u);
}
__device__ __forceinline__ u32 packbf_rtne(float flo, float fhi) {
    union { float f; unsigned i; } x0, x1; x0.f = flo; x1.f = fhi;
    u32 r0 = x0.i + 0x7fffu + ((x0.i >> 16) & 1u);
    u32 r1 = x1.i + 0x7fffu + ((x1.i >> 16) & 1u);
    return __builtin_amdgcn_perm(r1, r0, 0x07060302u);
}
__device__ __forceinline__ u32 act_pack(u32 u, float2 s0, float2 s1) {
    float2 f = act2(u, s0, s1);
    return packbf(f.x, f.y);
}
__device__ __forceinline__ short8v as_s8(uint4 v) {
    union { uint4 u; short8v s; } x; x.u = v; return x.s;
}

#define MFMA16(a,b,c) __builtin_amdgcn_mfma_f32_16x16x32_bf16(a,b,c,0,0,0)

// ---------------------------------------------------------------------------
// k_init: new_xyz + sample_idxs + w0t (xyz rows, fp32) + w0b/w1b/w2b (bf16)
// ---------------------------------------------------------------------------
__global__ void k_init(const float* __restrict__ xyz, const float* __restrict__ w0,
                       const float* __restrict__ w1, const float* __restrict__ w2,
                       float* __restrict__ out, float* __restrict__ w0t,
                       u16* __restrict__ w0b, u16* __restrict__ w1b,
                       u16* __restrict__ w2b) {
    int i = blockIdx.x * 256 + threadIdx.x;
    if (i < 49152) {
        int b = i / 3072, r = i % 3072;
        out[i] = xyz[b * 12288 + r];
        return;
    }
    int j = i - 49152;
    if (j < 16384) { out[OFF_SI + j] = (float)(j & 1023); return; }
    int e = j - 16384;
    if (e < 384) { w0t[e] = w0[(e & 127) * 131 + (e >> 7)]; return; }
    int f = e - 384;
    if (f < 16384) { w0b[f] = f2b(w0[(f >> 7) * 131 + 3 + (f & 127)]); return; }
    int h = f - 16384;
    if (h < 16384) { w1b[h] = f2b(w1[h]); return; }
    int k2 = h - 16384;
    if (k2 < 32768) { w2b[k2] = f2b(w2[k2]); }
}

// ---------------------------------------------------------------------------
// k_bqf1: FUSED ballquery + f1. 16 centers per bq block (wave scans 4 from
// one staged 48KB xyz tile). Grid 2048: even = f1 tile, odd = bq block.
// LDS = 48KB union (bq sx/sy/sz >= f1 abuf 17408 B).
// ---------------------------------------------------------------------------
__global__ __launch_bounds__(256) void k_bqf1(const float* __restrict__ xyz,
                                              const float* __restrict__ feat,
                                              const u16* __restrict__ w0b,
                                              float4* __restrict__ rel4,
                                              u16* __restrict__ F1) {
    __shared__ __align__(16) float smem[12288];   // 48 KB union
    int bid = blockIdx.x;
    int q2 = bid >> 1;
    int t = threadIdx.x;
    if (!(bid & 1)) {
        // ---------------- f1 tile q2: F1[n][co] = feat . w0b -------------
        uint4* abuf = (uint4*)smem;               // 64*17 uint4 = 17408 B
        int fb = q2;
        int w = t >> 6, lane = t & 63, q = lane >> 4, l16 = lane & 15;
        int cb = (w & 1) * 64, wm0 = (w >> 1) * 32;
        short8v bf[4][4];
#pragma unroll
        for (int ct = 0; ct < 4; ++ct)
#pragma unroll
            for (int k0 = 0; k0 < 4; ++k0)
                bf[ct][k0] = *(const short8v*)(w0b + (cb + ct * 16 + l16) * 128 + k0 * 32 + q * 8);
        int nl = t & 63, cg = t >> 6;
        const float* fcol = feat + (long)(fb >> 6) * (128 * 4096)
                                 + (long)(fb & 63) * 64 + nl;
#pragma unroll
        for (int pp = 0; pp < 4; ++pp) {
            int oct = cg + 4 * pp;
            float v[8];
#pragma unroll
            for (int r = 0; r < 8; ++r) v[r] = fcol[(long)(oct * 8 + r) * 4096];
            uint4 ov;
            ov.x = packbf_rtne(v[0], v[1]); ov.y = packbf_rtne(v[2], v[3]);
            ov.z = packbf_rtne(v[4], v[5]); ov.w = packbf_rtne(v[6], v[7]);
            abuf[nl * 17 + ((oct + nl) & 15)] = ov;
        }
        __syncthreads();
        f32x4 acc[2][4];
#pragma unroll
        for (int mt = 0; mt < 2; ++mt)
#pragma unroll
            for (int ct = 0; ct < 4; ++ct) acc[mt][ct] = (f32x4){0.f, 0.f, 0.f, 0.f};
#pragma unroll
        for (int mt = 0; mt < 2; ++mt) {
            int row = wm0 + mt * 16 + l16;
#pragma unroll
            for (int k0 = 0; k0 < 4; ++k0) {
                uint4 vv = abuf[row * 17 + ((k0 * 4 + q + row) & 15)];
                short8v af = as_s8(vv);
#pragma unroll
                for (int ct = 0; ct < 4; ++ct)
                    acc[mt][ct] = MFMA16(af, bf[ct][k0], acc[mt][ct]);
            }
        }
        long nbase = (long)fb * 64;
#pragma unroll
        for (int mt = 0; mt < 2; ++mt)
#pragma unroll
            for (int ct = 0; ct < 4; ++ct)
#pragma unroll
                for (int r = 0; r < 4; ++r)
                    F1[(nbase + wm0 + mt * 16 + q * 4 + r) * 128 + cb + ct * 16 + l16]
                        = f2b(acc[mt][ct][r]);
    } else {
        // -------- ballquery block q2: 16 centers, wave w scans 4 --------
        float* sx = smem;
        float* sy = smem + 4096;
        float* sz = smem + 8192;
        int w = t >> 6, lane = t & 63;
        int b = q2 >> 6;                   // 64 bq blocks per batch
        int pbase = (q2 & 63) * 16;
        const float* xb = xyz + (long)b * NN * 3;
        for (int i = t; i < NN; i += 256) {
            sx[i] = xb[3 * i]; sy[i] = xb[3 * i + 1]; sz[i] = xb[3 * i + 2];
        }
        __syncthreads();
        const float R2 = (float)(0.4 * 0.4);
#pragma unroll 1
        for (int k = 0; k < 4; ++k) {
            int p = pbase + 4 * w + k;
            float cx = sx[p], cy = sy[p], cz = sz[p];
            int o = (b * PP + p) * SS;
            int cnt = 0, firstn = 0;
            float fdx = 0.f, fdy = 0.f, fdz = 0.f;
            for (int c = 0; c < 64 && cnt < 32; ++c) {
                int n = c * 64 + lane;
                float dx = __fsub_rn(sx[n], cx);
                float dy = __fsub_rn(sy[n], cy);
                float dz = __fsub_rn(sz[n], cz);
                float d2 = __fadd_rn(__fadd_rn(__fmul_rn(dx, dx), __fmul_rn(dy, dy)),
                                     __fmul_rn(dz, dz));
                bool hit = d2 < R2;
                unsigned long long mask = __ballot(hit);
                if (mask) {
                    if (cnt == 0) {
                        int fl = __ffsll(mask) - 1;
                        firstn = c * 64 + fl;
                        fdx = __shfl(dx, fl); fdy = __shfl(dy, fl); fdz = __shfl(dz, fl);
                    }
                    int pos = cnt + __popcll(mask & ((1ull << lane) - 1ull));
                    if (hit && pos < 32) {
                        rel4[o + pos] = make_float4(dx, dy, dz, __int_as_float(n));
                    }
                    cnt += __popcll(mask);
                }
            }
            if (lane < 32 && lane >= cnt) {
                rel4[o + lane] = make_float4(fdx, fdy, fdz, __int_as_float(firstn));
            }
        }
    }
}

// ---------------------------------------------------------------------------
// k_y0stats: BN0 partials without materializing y0. rel4 staged to LDS;
// F1 (bf16) gathers batched 16-deep with one-group-ahead prefetch.
// ---------------------------------------------------------------------------
__global__ __launch_bounds__(256) void k_y0stats(const float4* __restrict__ rel4,
                                                 const float* __restrict__ w0t,
                                                 const u16* __restrict__ F1,
                                                 float* __restrict__ part,
                                                 float* __restrict__ partq) {
    __shared__ float4 srel[256];
    int t = threadIdx.x, w = t >> 6, lane = t & 63;
    int c0 = 2 * lane;
    float wx0 = w0t[c0],       wx1 = w0t[c0 + 1];
    float wy0 = w0t[128 + c0], wy1 = w0t[128 + c0 + 1];
    float wz0 = w0t[256 + c0], wz1 = w0t[256 + c0 + 1];
    int m0 = blockIdx.x * 256;
    srel[t] = rel4[m0 + t];
    __syncthreads();
    // whole block shares one batch b (256 | 32768)
    const u16* F1b = F1 + (((long)(blockIdx.x >> 7) * NN) << 7) + c0;
    float s1a = 0.f, s1b = 0.f, s2a = 0.f, s2b = 0.f;
    u32 f[16];
#pragma unroll
    for (int j = 0; j < 16; ++j) {
        int id = __float_as_int(srel[w + 4 * j].w);
        f[j] = *(const u32*)(F1b + ((long)id << 7));
    }
#pragma unroll
    for (int g = 0; g < 4; ++g) {
        u32 fn[16];
        if (g < 3) {
#pragma unroll
            for (int j = 0; j < 16; ++j) {
                int id = __float_as_int(srel[w + 4 * (16 * (g + 1) + j)].w);
                fn[j] = *(const u32*)(F1b + ((long)id << 7));
            }
        }
#pragma unroll
        for (int j = 0; j < 16; ++j) {
            float4 qv = srel[w + 4 * (16 * g + j)];
            float2 ff = unpk2(f[j]);
            float v0 = fmaf(wx0, qv.x, fmaf(wy0, qv.y, fmaf(wz0, qv.z, ff.x)));
            float v1 = fmaf(wx1, qv.x, fmaf(wy1, qv.y, fmaf(wz1, qv.z, ff.y)));
            s1a += v0; s2a = fmaf(v0, v0, s2a);
            s1b += v1; s2b = fmaf(v1, v1, s2b);
        }
#pragma unroll
        for (int j = 0; j < 16; ++j) f[j] = fn[j];
    }
    __shared__ float r1[128][4], r2[128][4];
    r1[c0][w] = s1a; r1[c0 + 1][w] = s1b;
    r2[c0][w] = s2a; r2[c0 + 1][w] = s2b;
    __syncthreads();
    if (t < 128) {
        float a1 = r1[t][0] + r1[t][1] + r1[t][2] + r1[t][3];
        float a2 = r2[t][0] + r2[t][1] + r2[t][2] + r2[t][3];
        part [(long)t * NBLK + blockIdx.x] = a1;
        partq[(long)t * NBLK + blockIdx.x] = a2;
    }
}

// ---------------------------------------------------------------------------
// k_bnfin: reduce per-channel partials -> (scale, shift). grid = #channels.
// ---------------------------------------------------------------------------
__global__ void k_bnfin(const float* __restrict__ part, const float* __restrict__ partq,
                        const float* __restrict__ g, const float* __restrict__ beta,
                        float* __restrict__ st, int nblk) {
    int co = blockIdx.x, t = threadIdx.x;
    const float* p1 = part + (long)co * NBLK;
    const float* p2 = partq + (long)co * NBLK;
    float s1 = 0.f, s2 = 0.f;
    for (int j = t; j < nblk; j += 256) { s1 += p1[j]; s2 += p2[j]; }
    __shared__ float r1[256], r2[256];
    r1[t] = s1; r2[t] = s2; __syncthreads();
    for (int off = 128; off > 0; off >>= 1) {
        if (t < off) { r1[t] += r1[t + off]; r2[t] += r2[t + off]; }
        __syncthreads();
    }
    if (t == 0) {
        const float inv = 1.f / (float)MM;
        float mean = r1[0] * inv;
        float var = r2[0] * inv - mean * mean;
        float sc = g[co] * rsqrtf(var + 1e-5f);
        st[2 * co] = sc;
        st[2 * co + 1] = fmaf(-mean, sc, beta[co]);
    }
}

// ---------------------------------------------------------------------------
// k_conv1: y1 = W1 . act0(y0), act0(y0) reconstructed in staging from
// srel (LDS copy of rel4) + F1 (bf16) gather + st0. r7/r9-PROVEN config,
// REVERTED EXACTLY (best measured: 66 us, total 279.2). Falsified-lever
// ledger, do not repeat: (r5) smaller blocks -> cross-XCD partial-line
// false sharing; (r6) stride-16 -> 1M bank conflicts; (r6/r10)
// launch_bounds >=4 -> VGPR clamp <=64 -> scratch spill (FETCH 320-346MB);
// (r11) shfl-paired u32 stores -> VALU cost > coalescing gain (stores
// already 32B-segmented either way).
// ---------------------------------------------------------------------------
__global__ __launch_bounds__(256, 3) void k_conv1(const float4* __restrict__ rel4,
                                                  const u16* __restrict__ F1,
                                                  const u16* __restrict__ w1b,
                                                  const float* __restrict__ w0t,
                                                  const float* __restrict__ st0,
                                                  u16* __restrict__ y,
                                                  float* __restrict__ part,
                                                  float* __restrict__ partq) {
    __shared__ u32 abuf[2][64 * 17 * 4];
    __shared__ float4 srel[512];
    __shared__ float sredA[4][64], sredB[4][64];
    int t = threadIdx.x;
    int w = t >> 6, lane = t & 63, q = lane >> 4, l16 = lane & 15;
    int wm0 = (w >> 1) * 32, cb = (w & 1) * 64;
    short8v bf[4][4];
#pragma unroll
    for (int ct = 0; ct < 4; ++ct)
#pragma unroll
        for (int k0 = 0; k0 < 4; ++k0)
            bf[ct][k0] = *(const short8v*)(w1b + (cb + ct * 16 + l16) * 128 + k0 * 32 + q * 8);
    // staging constants for cols (2*lane, 2*lane+1)
    int c0 = 2 * lane;
    float wx0 = w0t[c0],       wx1 = w0t[c0 + 1];
    float wy0 = w0t[128 + c0], wy1 = w0t[128 + c0 + 1];
    float wz0 = w0t[256 + c0], wz1 = w0t[256 + c0 + 1];
    float4 s4 = *(const float4*)(st0 + 2 * c0);   // sc0, sh0, sc1, sh1
    int m0b = blockIdx.x * 512;
    // stage rel4 for the whole block into LDS (coalesced, once)
    srel[t] = rel4[m0b + t];
    srel[t + 256] = rel4[m0b + t + 256];
    __syncthreads();
    // whole block shares one batch b (512 | 32768)
    const u16* F1b = F1 + (((long)(blockIdx.x >> 6) * NN) << 7) + c0;
    float s1[4] = {0.f, 0.f, 0.f, 0.f}, s2[4] = {0.f, 0.f, 0.f, 0.f};
    int rbase = w * 16;
    int cg = lane >> 2, wsel = lane & 3;
    // prologue: issue chunk-0 gathers
    u32 f[16];
#pragma unroll
    for (int j = 0; j < 16; ++j) {
        int id = __float_as_int(srel[rbase + j].w);
        f[j] = *(const u32*)(F1b + ((long)id << 7));
    }
    for (int c = 0; c < 8; ++c) {
        int m0 = m0b + c * 64;
        u32* ab = abuf[c & 1];
        // consume chunk c: reconstruct act0(y0) rows, write swizzled LDS
#pragma unroll
        for (int j = 0; j < 16; ++j) {
            int r = rbase + j;
            float4 qv = srel[c * 64 + r];
            float2 ff = unpk2(f[j]);
            float v0 = fmaf(wx0, qv.x, fmaf(wy0, qv.y, fmaf(wz0, qv.z, ff.x)));
            float v1 = fmaf(wx1, qv.x, fmaf(wy1, qv.y, fmaf(wz1, qv.z, ff.y)));
            float a0 = fmaxf(fmaf(s4.x, v0, s4.y), 0.f);
            float a1 = fmaxf(fmaf(s4.z, v1, s4.w), 0.f);
            ab[(r * 17 + ((cg + r) & 15)) * 4 + wsel] = packbf(a0, a1);
        }
        __syncthreads();
        // prefetch chunk c+1 (latency hides under MFMA + epilogue)
        if (c < 7) {
#pragma unroll
            for (int j = 0; j < 16; ++j) {
                int id = __float_as_int(srel[(c + 1) * 64 + rbase + j].w);
                f[j] = *(const u32*)(F1b + ((long)id << 7));
            }
        }
        f32x4 acc[2][4];
#pragma unroll
        for (int mt = 0; mt < 2; ++mt)
#pragma unroll
            for (int ct = 0; ct < 4; ++ct) acc[mt][ct] = (f32x4){0.f, 0.f, 0.f, 0.f};
        const uint4* ab4 = (const uint4*)ab;
#pragma unroll
        for (int mt = 0; mt < 2; ++mt) {
            int row = wm0 + mt * 16 + l16;
#pragma unroll
            for (int k0 = 0; k0 < 4; ++k0) {
                uint4 v = ab4[row * 17 + ((k0 * 4 + q + row) & 15)];
                short8v af = as_s8(v);
#pragma unroll
                for (int ct = 0; ct < 4; ++ct)
                    acc[mt][ct] = MFMA16(af, bf[ct][k0], acc[mt][ct]);
            }
        }
#pragma unroll
        for (int mt = 0; mt < 2; ++mt)
#pragma unroll
            for (int ct = 0; ct < 4; ++ct)
#pragma unroll
                for (int r = 0; r < 4; ++r) {
                    float v = acc[mt][ct][r];
                    y[(long)(m0 + wm0 + mt * 16 + q * 4 + r) * 128 + cb + ct * 16 + l16] = f2b(v);
                    s1[ct] += v; s2[ct] = fmaf(v, v, s2[ct]);
                }
    }
#pragma unroll
    for (int ct = 0; ct < 4; ++ct) {
        float a = s1[ct], b = s2[ct];
        a += __shfl_xor(a, 16); a += __shfl_xor(a, 32);
        b += __shfl_xor(b, 16); b += __shfl_xor(b, 32);
        if (lane < 16) { sredA[w][ct * 16 + l16] = a; sredB[w][ct * 16 + l16] = b; }
    }
    __syncthreads();
    if (t < 128) {
        int h = t >> 6, cl = t & 63;
        part [(long)t * NBLK + blockIdx.x] = sredA[h][cl] + sredA[h + 2][cl];
        partq[(long)t * NBLK + blockIdx.x] = sredB[h][cl] + sredB[h + 2][cl];
    }
}

// ---------------------------------------------------------------------------
// k_conv2pool: proven structure (B resident bf[4][4], wave = 64m x 64co,
// rotation swizzle, fused BN2 stat partials, 512 rows, grid 1024, 8 chunks)
// + r7 signed-extreme pooling: sign(sc2)=sign(g2) known pre-stats, store
// e = max over rows of (sgn*v) (== mx if g2>=0, == -mn if g2<0, exact).
// ---------------------------------------------------------------------------
__global__ __launch_bounds__(256) void k_conv2pool(const u16* __restrict__ y1,
                                                   const u16* __restrict__ w2b,
                                                   const float* __restrict__ st1,
                                                   const float* __restrict__ g2,
                                                   float* __restrict__ rawext,
                                                   float* __restrict__ part,
                                                   float* __restrict__ partq) {
    __shared__ uint4 abuf[2][64 * 17];
    __shared__ float2 sst[128];
    __shared__ float sredA[4][64], sredB[4][64];
    int t = threadIdx.x;
    if (t < 128) sst[t] = ((const float2*)st1)[t];
    int w = t >> 6, lane = t & 63, q = lane >> 4, l16 = lane & 15;
    int cb = w * 64;
    short8v bf[4][4];
#pragma unroll
    for (int ct = 0; ct < 4; ++ct)
#pragma unroll
        for (int k0 = 0; k0 < 4; ++k0)
            bf[ct][k0] = *(const short8v*)(w2b + (cb + ct * 16 + l16) * 128 + k0 * 32 + q * 8);
    // per-ct sign of g2 for this lane's output channels
    float sg[4];
#pragma unroll
    for (int ct = 0; ct < 4; ++ct)
        sg[ct] = g2[cb + ct * 16 + l16] >= 0.f ? 1.f : -1.f;
    __syncthreads();
    long m0b = (long)blockIdx.x * 512;
    int sr = t >> 4, sc16 = t & 15;
    float s1[4] = {0.f, 0.f, 0.f, 0.f}, s2[4] = {0.f, 0.f, 0.f, 0.f};
    for (int c = 0; c < 8; ++c) {
        long m0 = m0b + c * 64;
        uint4* ab = abuf[c & 1];
        const uint4* gsrc = (const uint4*)y1;
#pragma unroll
        for (int p = 0; p < 4; ++p) {
            int r = p * 16 + sr;
            uint4 d = gsrc[(m0 + r) * 16 + sc16];
            uint4 o;
            o.x = act_pack(d.x, sst[sc16 * 8 + 0], sst[sc16 * 8 + 1]);
            o.y = act_pack(d.y, sst[sc16 * 8 + 2], sst[sc16 * 8 + 3]);
            o.z = act_pack(d.z, sst[sc16 * 8 + 4], sst[sc16 * 8 + 5]);
            o.w = act_pack(d.w, sst[sc16 * 8 + 6], sst[sc16 * 8 + 7]);
            ab[r * 17 + ((sc16 + r) & 15)] = o;
        }
        __syncthreads();
        f32x4 acc[4][4];
#pragma unroll
        for (int mt = 0; mt < 4; ++mt)
#pragma unroll
            for (int ct = 0; ct < 4; ++ct) acc[mt][ct] = (f32x4){0.f, 0.f, 0.f, 0.f};
#pragma unroll
        for (int mt = 0; mt < 4; ++mt) {
            int row = mt * 16 + l16;
#pragma unroll
            for (int k0 = 0; k0 < 4; ++k0) {
                uint4 v = ab[row * 17 + ((k0 * 4 + q + row) & 15)];
                short8v af = as_s8(v);
#pragma unroll
                for (int ct = 0; ct < 4; ++ct)
                    acc[mt][ct] = MFMA16(af, bf[ct][k0], acc[mt][ct]);
            }
        }
        // pooling per 32-row group (mt pairs) + stats over all rows
#pragma unroll
        for (int ct = 0; ct < 4; ++ct) {
            float s = sg[ct];
#pragma unroll
            for (int g = 0; g < 2; ++g) {
                f32x4 a0 = acc[2 * g][ct], a1 = acc[2 * g + 1][ct];
                s1[ct] += a0[0] + a0[1] + a0[2] + a0[3] + a1[0] + a1[1] + a1[2] + a1[3];
                s2[ct] = fmaf(a0[0], a0[0], s2[ct]); s2[ct] = fmaf(a0[1], a0[1], s2[ct]);
                s2[ct] = fmaf(a0[2], a0[2], s2[ct]); s2[ct] = fmaf(a0[3], a0[3], s2[ct]);
                s2[ct] = fmaf(a1[0], a1[0], s2[ct]); s2[ct] = fmaf(a1[1], a1[1], s2[ct]);
                s2[ct] = fmaf(a1[2], a1[2], s2[ct]); s2[ct] = fmaf(a1[3], a1[3], s2[ct]);
                float e = fmaxf(fmaxf(fmaxf(s * a0[0], s * a0[1]), fmaxf(s * a0[2], s * a0[3])),
                                fmaxf(fmaxf(s * a1[0], s * a1[1]), fmaxf(s * a1[2], s * a1[3])));
                e = fmaxf(e, __shfl_xor(e, 16)); e = fmaxf(e, __shfl_xor(e, 32));
                if (lane < 16) {
                    long bp = (long)blockIdx.x * 16 + c * 2 + g;
                    rawext[bp * 256 + cb + ct * 16 + l16] = e;
                }
            }
        }
    }
#pragma unroll
    for (int ct = 0; ct < 4; ++ct) {
        float a = s1[ct], b = s2[ct];
        a += __shfl_xor(a, 16); a += __shfl_xor(a, 32);
        b += __shfl_xor(b, 16); b += __shfl_xor(b, 32);
        if (lane < 16) { sredA[w][ct * 16 + l16] = a; sredB[w][ct * 16 + l16] = b; }
    }
    __syncthreads();
    {
        part [(long)t * NBLK + blockIdx.x] = sredA[t >> 6][t & 63];
        partq[(long)t * NBLK + blockIdx.x] = sredB[t >> 6][t & 63];
    }
}

// ---------------------------------------------------------------------------
// k_final: e is the signed extreme (sgn*max(sgn*v)); recover the needed
// extreme exactly: x = sc>0 ? e : -e. z = relu(sc*x + sh); transpose to
// out[b][co][p].
// ---------------------------------------------------------------------------
__global__ void k_final(const float* __restrict__ rawext,
                        const float* __restrict__ st2, float* __restrict__ out) {
    __shared__ float tile[32][33];
    int b = blockIdx.x >> 8;
    int p0 = ((blockIdx.x >> 3) & 31) * 32;
    int c0 = (blockIdx.x & 7) * 32;
    int j = threadIdx.x & 31, i0 = threadIdx.x >> 5;
    float sc = st2[2 * (c0 + j)], sh = st2[2 * (c0 + j) + 1];
#pragma unroll
    for (int rr = 0; rr < 4; ++rr) {
        int i = i0 + rr * 8;
        long idx = ((long)(b * 1024 + p0 + i)) * 256 + c0 + j;
        float e = rawext[idx];
        float x = sc > 0.f ? e : -e;
        tile[i][j] = fmaxf(fmaf(sc, x, sh), 0.f);
    }
    __syncthreads();
#pragma unroll
    for (int rr = 0; rr < 4; ++rr) {
        int i = i0 + rr * 8;
        out[OFF_NF + (long)b * 262144 + (c0 + i) * 1024 + p0 + j] = tile[j][i];
    }
}

// ---------------------------------------------------------------------------
extern "C" void kernel_launch(void* const* d_in, const int* in_sizes, int n_in,
                              void* d_out, int out_size, void* d_ws, size_t ws_size,
                              hipStream_t stream) {
    (void)in_sizes; (void)n_in; (void)out_size; (void)ws_size;
    const float* xyz  = (const float*)d_in[0];
    const float* feat = (const float*)d_in[1];
    const float* w0   = (const float*)d_in[3];
    const float* g0   = (const float*)d_in[5];
    const float* be0  = (const float*)d_in[6];
    const float* w1   = (const float*)d_in[7];
    const float* g1   = (const float*)d_in[9];
    const float* be1  = (const float*)d_in[10];
    const float* w2   = (const float*)d_in[11];
    const float* g2   = (const float*)d_in[13];
    const float* be2  = (const float*)d_in[14];
    float* out = (float*)d_out;

    char* ws = (char*)d_ws;
    size_t off = 0;
    auto alloc = [&](size_t bytes) -> void* {
        void* p = ws + off;
        off = (off + bytes + 4095) & ~(size_t)4095;
        return p;
    };
    float4* rel4  = (float4*)alloc((size_t)MM * 16);          // 8 MB
    float* w0t    = (float*)alloc(3 * 128 * 4);
    u16*   w0b    = (u16*)  alloc(128 * 128 * 2);
    u16*   w1b    = (u16*)  alloc(128 * 128 * 2);
    u16*   w2b    = (u16*)  alloc(256 * 128 * 2);
    float* st0    = (float*)alloc(128 * 2 * 4);
    float* st1    = (float*)alloc(128 * 2 * 4);
    float* st2    = (float*)alloc(256 * 2 * 4);
    float* part   = (float*)alloc((size_t)256 * NBLK * 4);    // 8 MB
    float* partq  = (float*)alloc((size_t)256 * NBLK * 4);    // 8 MB
    u16*   F1     = (u16*)  alloc((size_t)BB * NN * 128 * 2); // 16.8 MB (bf16)
    float* rawext = (float*)alloc((size_t)BB * PP * 256 * 4); // 16 MB
    u16*   bufA   = (u16*)  alloc((size_t)MM * 128 * 2);      // 134 MB (y1)

    k_init<<<514, 256, 0, stream>>>(xyz, w0, w1, w2, out, w0t, w0b, w1b, w2b);
    k_bqf1<<<2048, 256, 0, stream>>>(xyz, feat, w0b, rel4, F1);
    k_y0stats<<<2048, 256, 0, stream>>>(rel4, w0t, F1, part, partq);
    k_bnfin<<<128, 256, 0, stream>>>(part, partq, g0, be0, st0, 2048);
    k_conv1<<<1024, 256, 0, stream>>>(rel4, F1, w1b, w0t, st0, bufA, part, partq);
    k_bnfin<<<128, 256, 0, stream>>>(part, partq, g1, be1, st1, 1024);
    k_conv2pool<<<1024, 256, 0, stream>>>(bufA, w2b, st1, g2, rawext, part, partq);
    k_bnfin<<<256, 256, 0, stream>>>(part, partq, g2, be2, st2, 1024);
    k_final<<<4096, 256, 0, stream>>>(rawext, st2, out);
}